// Round 1
// baseline (4072.949 us; speedup 1.0000x reference)
//
#include <hip/hip_runtime.h>
#include <math.h>

#define DIMV 200

static __device__ __forceinline__ int lower_bound(const int* __restrict__ a, int n, int key) {
    int lo = 0, hi = n;
    while (lo < hi) {
        int mid = (lo + hi) >> 1;
        if (a[mid] < key) lo = mid + 1; else hi = mid;
    }
    return lo;
}

static __device__ __forceinline__ float gate_fn(float u, float logit) {
    // bias = 1e-4: eps = (2b-1)*u + (1-b); sigmoid((log(eps)-log1p(-eps)+logit)/0.5)
    float ee = fmaf(u, -0.9998f, 0.9999f);
    float g  = (logf(ee) - log1pf(-ee) + logit) * 2.0f;
    return 1.0f / (1.0f + expf(-g));
}

// ---------------------------------------------------------------------------
// Node MLP + concrete gate.  grid = (N/16, 2), block = 256.
// h = relu(e0 @ W1[i] + b1[i]); logit = h @ W2[i] + b2[i]; mask = gate
// Tile: 16 rows x 200 cols, thread = 4 rows x 4 contiguous cols, K chunks of 40.
// ---------------------------------------------------------------------------
__global__ __launch_bounds__(256) void node_mlp_kernel(
    const float* __restrict__ e0, const float* __restrict__ W1,
    const float* __restrict__ b1, const float* __restrict__ W2,
    const float* __restrict__ b2, const float* __restrict__ eps,
    float* __restrict__ mask_out, int N)
{
    const int KC = 40;
    __shared__ __align__(16) float W1s[KC * 200];   // [k][j]
    __shared__ __align__(16) float cats[16 * KC];   // [r][k]
    __shared__ float red[16 * 50];

    const int i  = blockIdx.y;
    const int r0 = blockIdx.x * 16;
    const int t  = threadIdx.x;
    const int cg = t % 50;          // col group (cols cg*4 .. cg*4+3)
    const int rg = t / 50;          // row group (rows rg*4 .. rg*4+3), valid t<200
    const int j0 = cg * 4;
    const float* W1i = W1 + i * 200 * 200;

    float acc[4][4];
#pragma unroll
    for (int a = 0; a < 4; a++)
#pragma unroll
        for (int c = 0; c < 4; c++) acc[a][c] = 0.f;

    for (int k0 = 0; k0 < 200; k0 += KC) {
        for (int f = t; f < KC * 200; f += 256) W1s[f] = W1i[k0 * 200 + f];
        for (int f = t; f < 16 * KC; f += 256) {
            int rr = f / KC, k = f % KC;
            int row = r0 + rr; if (row >= N) row = 0;
            cats[f] = e0[row * 200 + k0 + k];
        }
        __syncthreads();
        if (t < 200) {
            for (int k = 0; k < KC; k += 4) {
                float ck[4][4];
#pragma unroll
                for (int ri = 0; ri < 4; ri++) {
                    float4 cc = *(const float4*)&cats[(rg * 4 + ri) * KC + k];
                    ck[ri][0] = cc.x; ck[ri][1] = cc.y; ck[ri][2] = cc.z; ck[ri][3] = cc.w;
                }
#pragma unroll
                for (int kk = 0; kk < 4; kk++) {
                    float4 w = *(const float4*)&W1s[(k + kk) * 200 + j0];
#pragma unroll
                    for (int ri = 0; ri < 4; ri++) {
                        float cv = ck[ri][kk];
                        acc[ri][0] = fmaf(cv, w.x, acc[ri][0]);
                        acc[ri][1] = fmaf(cv, w.y, acc[ri][1]);
                        acc[ri][2] = fmaf(cv, w.z, acc[ri][2]);
                        acc[ri][3] = fmaf(cv, w.w, acc[ri][3]);
                    }
                }
            }
        }
        __syncthreads();
    }

    if (t < 200) {
        float bb[4], ww[4];
#pragma unroll
        for (int c = 0; c < 4; c++) { bb[c] = b1[i * 200 + j0 + c]; ww[c] = W2[i * 200 + j0 + c]; }
#pragma unroll
        for (int ri = 0; ri < 4; ri++) {
            float p = 0.f;
#pragma unroll
            for (int c = 0; c < 4; c++) {
                float h = fmaxf(acc[ri][c] + bb[c], 0.f);
                p = fmaf(h, ww[c], p);
            }
            red[(rg * 4 + ri) * 50 + cg] = p;
        }
    }
    __syncthreads();
    if (t < 16) {
        int n = r0 + t;
        if (n < N) {
            float s = b2[i];
            for (int c = 0; c < 50; c++) s += red[t * 50 + c];
            mask_out[i * N + n] = gate_fn(eps[i * N + n], s);
        }
    }
}

// ---------------------------------------------------------------------------
// Edge MLP + gate (i=1 slice only; i=0 edge mask is dead in the reference).
// cat = [e0[row], e0[col]] (400); he = relu(cat@W1+b1); logit = he@W2+b2.
// grid = ceil(E/16), block = 256.  K chunks of 40 never straddle the 200 split.
// ---------------------------------------------------------------------------
__global__ __launch_bounds__(256) void edge_mlp_kernel(
    const float* __restrict__ e0,
    const float* __restrict__ W1,   // already offset to i=1: (400,200)
    const float* __restrict__ b1,   // offset (200)
    const float* __restrict__ W2,   // offset (200)
    const float* __restrict__ b2,   // offset (1)
    const float* __restrict__ eps,  // offset (E)
    const int* __restrict__ erow, const int* __restrict__ ecol,
    float* __restrict__ mask_out, int E)
{
    const int KC = 40;
    __shared__ __align__(16) float W1s[KC * 200];
    __shared__ __align__(16) float cats[16 * KC];
    __shared__ float red[16 * 50];
    __shared__ int rowv[16], colv[16];

    const int e0i = blockIdx.x * 16;
    const int t   = threadIdx.x;
    const int cg  = t % 50;
    const int rg  = t / 50;
    const int j0  = cg * 4;

    if (t < 16) {
        int e = e0i + t;
        rowv[t] = (e < E) ? erow[e] : 0;
        colv[t] = (e < E) ? ecol[e] : 0;
    }
    __syncthreads();

    float acc[4][4];
#pragma unroll
    for (int a = 0; a < 4; a++)
#pragma unroll
        for (int c = 0; c < 4; c++) acc[a][c] = 0.f;

    for (int k0 = 0; k0 < 400; k0 += KC) {
        for (int f = t; f < KC * 200; f += 256) W1s[f] = W1[k0 * 200 + f];
        const int useCol = (k0 >= 200);
        const int kbase  = useCol ? (k0 - 200) : k0;
        for (int f = t; f < 16 * KC; f += 256) {
            int rr = f / KC, k = f % KC;
            int node = useCol ? colv[rr] : rowv[rr];
            cats[f] = e0[node * 200 + kbase + k];
        }
        __syncthreads();
        if (t < 200) {
            for (int k = 0; k < KC; k += 4) {
                float ck[4][4];
#pragma unroll
                for (int ri = 0; ri < 4; ri++) {
                    float4 cc = *(const float4*)&cats[(rg * 4 + ri) * KC + k];
                    ck[ri][0] = cc.x; ck[ri][1] = cc.y; ck[ri][2] = cc.z; ck[ri][3] = cc.w;
                }
#pragma unroll
                for (int kk = 0; kk < 4; kk++) {
                    float4 w = *(const float4*)&W1s[(k + kk) * 200 + j0];
#pragma unroll
                    for (int ri = 0; ri < 4; ri++) {
                        float cv = ck[ri][kk];
                        acc[ri][0] = fmaf(cv, w.x, acc[ri][0]);
                        acc[ri][1] = fmaf(cv, w.y, acc[ri][1]);
                        acc[ri][2] = fmaf(cv, w.z, acc[ri][2]);
                        acc[ri][3] = fmaf(cv, w.w, acc[ri][3]);
                    }
                }
            }
        }
        __syncthreads();
    }

    if (t < 200) {
        float bb[4], ww[4];
#pragma unroll
        for (int c = 0; c < 4; c++) { bb[c] = b1[j0 + c]; ww[c] = W2[j0 + c]; }
#pragma unroll
        for (int ri = 0; ri < 4; ri++) {
            float p = 0.f;
#pragma unroll
            for (int c = 0; c < 4; c++) {
                float h = fmaxf(acc[ri][c] + bb[c], 0.f);
                p = fmaf(h, ww[c], p);
            }
            red[(rg * 4 + ri) * 50 + cg] = p;
        }
    }
    __syncthreads();
    if (t < 16) {
        int e = e0i + t;
        if (e < E) {
            float s = b2[0];
            for (int c = 0; c < 50; c++) s += red[t * 50 + c];
            mask_out[e] = gate_fn(eps[e], s);
        }
    }
}

// ---------------------------------------------------------------------------
// SpMM over sorted COO: out[r,:] = sum_e val[e]*(emask?emask[e]:1)*x[col[e],:]
// One block per output row; row range found by binary search.
// ---------------------------------------------------------------------------
__global__ __launch_bounds__(256) void spmm_kernel(
    const float* __restrict__ x, const int* __restrict__ row,
    const int* __restrict__ col, const float* __restrict__ val,
    const float* __restrict__ emask, int E, float* __restrict__ out)
{
    __shared__ int bnds[2];
    const int r = blockIdx.x;
    if (threadIdx.x == 0) {
        bnds[0] = lower_bound(row, E, r);
        bnds[1] = lower_bound(row, E, r + 1);
    }
    __syncthreads();
    const int d = threadIdx.x;
    if (d >= DIMV) return;
    const int lo = bnds[0], hi = bnds[1];
    float acc = 0.f;
    if (emask) {
        for (int e = lo; e < hi; e++)
            acc = fmaf(val[e] * emask[e], x[col[e] * DIMV + d], acc);
    } else {
        for (int e = lo; e < hi; e++)
            acc = fmaf(val[e], x[col[e] * DIMV + d], acc);
    }
    out[r * DIMV + d] = acc;
}

// out[r,:] = m[r]*x[r,:] + (1-m[r]) * (rw-SpMM of x)[r,:]
__global__ __launch_bounds__(256) void rw_combine_kernel(
    const float* __restrict__ x, const int* __restrict__ row,
    const int* __restrict__ col, const float* __restrict__ val,
    int E, const float* __restrict__ mask, float* __restrict__ out)
{
    __shared__ int bnds[2];
    const int r = blockIdx.x;
    if (threadIdx.x == 0) {
        bnds[0] = lower_bound(row, E, r);
        bnds[1] = lower_bound(row, E, r + 1);
    }
    __syncthreads();
    const int d = threadIdx.x;
    if (d >= DIMV) return;
    const int lo = bnds[0], hi = bnds[1];
    float acc = 0.f;
    for (int e = lo; e < hi; e++)
        acc = fmaf(val[e], x[col[e] * DIMV + d], acc);
    const float m = mask[r];
    out[r * DIMV + d] = m * x[r * DIMV + d] + (1.f - m) * acc;
}

// ---------------------------------------------------------------------------
// self_hr[b,:] = e0[sub[b],:] @ rel_emb[rel[b]].reshape(200,200)
// ---------------------------------------------------------------------------
__global__ __launch_bounds__(256) void selfhr_kernel(
    const float* __restrict__ e0, const float* __restrict__ rel_emb,
    const int* __restrict__ sub, const int* __restrict__ rel,
    float* __restrict__ out)
{
    const int b = blockIdx.x;
    __shared__ float lhs[DIMV];
    const int t = threadIdx.x;
    if (t < DIMV) lhs[t] = e0[sub[b] * DIMV + t];
    __syncthreads();
    if (t >= DIMV) return;
    const float* R = rel_emb + (size_t)rel[b] * (DIMV * DIMV);
    float acc = 0.f;
    for (int dd = 0; dd < DIMV; dd++)
        acc = fmaf(lhs[dd], R[dd * DIMV + t], acc);
    out[b * DIMV + t] = acc;
}

// ---------------------------------------------------------------------------
// scores = sigmoid(self_hr @ e0^T): (1024,200)@(200,N).
// 64b x 64n tiles, thread = 4x4 (rows strided by 16 to avoid bank conflicts),
// K in 2 chunks of 100, LDS stride 108.
// ---------------------------------------------------------------------------
__global__ __launch_bounds__(256) void scores_kernel(
    const float* __restrict__ hr, const float* __restrict__ e0,
    float* __restrict__ scores, int N)
{
    const int ST = 108;
    __shared__ __align__(16) float hs[64 * ST];
    __shared__ __align__(16) float es[64 * ST];
    const int n0 = blockIdx.x * 64;
    const int b0 = blockIdx.y * 64;
    const int t  = threadIdx.x;
    const int bg = t >> 4;      // 0..15
    const int ng = t & 15;      // 0..15

    float acc[4][4];
#pragma unroll
    for (int a = 0; a < 4; a++)
#pragma unroll
        for (int c = 0; c < 4; c++) acc[a][c] = 0.f;

    for (int kc = 0; kc < 200; kc += 100) {
        for (int f = t; f < 64 * 100; f += 256) {
            int rr = f / 100, k = f % 100;
            hs[rr * ST + k] = hr[(b0 + rr) * 200 + kc + k];
            int n = n0 + rr;
            es[rr * ST + k] = (n < N) ? e0[n * 200 + kc + k] : 0.f;
        }
        __syncthreads();
        for (int k = 0; k < 100; k += 4) {
            float4 av[4], bv[4];
#pragma unroll
            for (int q = 0; q < 4; q++) av[q] = *(const float4*)&hs[(bg + 16 * q) * ST + k];
#pragma unroll
            for (int q = 0; q < 4; q++) bv[q] = *(const float4*)&es[(ng + 16 * q) * ST + k];
#pragma unroll
            for (int bi = 0; bi < 4; bi++)
#pragma unroll
                for (int ni = 0; ni < 4; ni++) {
                    acc[bi][ni] = fmaf(av[bi].x, bv[ni].x, acc[bi][ni]);
                    acc[bi][ni] = fmaf(av[bi].y, bv[ni].y, acc[bi][ni]);
                    acc[bi][ni] = fmaf(av[bi].z, bv[ni].z, acc[bi][ni]);
                    acc[bi][ni] = fmaf(av[bi].w, bv[ni].w, acc[bi][ni]);
                }
        }
        __syncthreads();
    }

#pragma unroll
    for (int bi = 0; bi < 4; bi++) {
        int b = b0 + bg + 16 * bi;
#pragma unroll
        for (int ni = 0; ni < 4; ni++) {
            int n = n0 + ng + 16 * ni;
            if (n < N)
                scores[(size_t)b * N + n] = 1.f / (1.f + expf(-acc[bi][ni]));
        }
    }
}

extern "C" void kernel_launch(void* const* d_in, const int* in_sizes, int n_in,
                              void* d_out, int out_size, void* d_ws, size_t ws_size,
                              hipStream_t stream)
{
    const float* e0       = (const float*)d_in[0];
    const float* rel_emb  = (const float*)d_in[1];
    const float* node_W1  = (const float*)d_in[2];
    const float* node_b1  = (const float*)d_in[3];
    const float* node_W2  = (const float*)d_in[4];
    const float* node_b2  = (const float*)d_in[5];
    const float* edge_W1  = (const float*)d_in[6];
    const float* edge_b1  = (const float*)d_in[7];
    const float* edge_W2  = (const float*)d_in[8];
    const float* edge_b2  = (const float*)d_in[9];
    const int*   adj_row  = (const int*)d_in[10];
    const int*   adj_col  = (const int*)d_in[11];
    const float* adj_val  = (const float*)d_in[12];
    const int*   rw_row   = (const int*)d_in[13];
    const int*   rw_col   = (const int*)d_in[14];
    const float* rw_val   = (const float*)d_in[15];
    const float* node_eps = (const float*)d_in[16];
    const float* edge_eps = (const float*)d_in[17];
    const int*   sub      = (const int*)d_in[18];
    const int*   rel      = (const int*)d_in[19];

    const int E   = in_sizes[10];
    const int Erw = in_sizes[13];
    const int N   = in_sizes[0] / DIMV;   // 50000
    const int B   = in_sizes[18];         // 1024

    // workspace: masks + self_hr only (~2.8 MB)
    float* ws        = (float*)d_ws;
    float* node_mask = ws;                 // 2*N
    float* edge_mask = ws + 2 * (size_t)N; // E   (i=1 mask)
    float* hrbuf     = edge_mask + E;      // B*200

    // output layout: scores (B*N), x_nd (N*200), x_ed (N*200)
    float* out    = (float*)d_out;
    float* scores = out;
    float* x_nd   = out + (size_t)B * N;
    float* x_ed   = x_nd + (size_t)N * DIMV;
    // scores region doubles as two N*200 temporaries until the GEMM runs
    float* T  = scores;
    float* T2 = scores + (size_t)N * DIMV;

    // 1. node masks (both i)
    node_mlp_kernel<<<dim3((N + 15) / 16, 2), 256, 0, stream>>>(
        e0, node_W1, node_b1, node_W2, node_b2, node_eps, node_mask, N);

    // 2. edge mask, i=1 slice only
    edge_mlp_kernel<<<dim3((E + 15) / 16), 256, 0, stream>>>(
        e0, edge_W1 + 400 * 200, edge_b1 + 200, edge_W2 + 200, edge_b2 + 1,
        edge_eps + (size_t)E, adj_row, adj_col, edge_mask, E);

    // 3-5. edge-drop branch: x_ed = adj_spmm(masked, rw_spmm(rw_spmm(e0)))
    spmm_kernel<<<N, 256, 0, stream>>>(e0,   rw_row, rw_col, rw_val, nullptr, Erw, x_nd);
    spmm_kernel<<<N, 256, 0, stream>>>(x_nd, rw_row, rw_col, rw_val, nullptr, Erw, T);
    spmm_kernel<<<N, 256, 0, stream>>>(T, adj_row, adj_col, adj_val, edge_mask, E, x_ed);

    // 6-9. node-drop branch
    rw_combine_kernel<<<N, 256, 0, stream>>>(e0, rw_row, rw_col, rw_val, Erw, node_mask,     x_nd);
    spmm_kernel      <<<N, 256, 0, stream>>>(x_nd, adj_row, adj_col, adj_val, nullptr, E,    T);
    rw_combine_kernel<<<N, 256, 0, stream>>>(T,  rw_row, rw_col, rw_val, Erw, node_mask + N, T2);
    spmm_kernel      <<<N, 256, 0, stream>>>(T2, adj_row, adj_col, adj_val, nullptr, E,      x_nd);

    // 10. self_hr
    selfhr_kernel<<<B, 256, 0, stream>>>(e0, rel_emb, sub, rel, hrbuf);

    // 11. scores = sigmoid(self_hr @ e0^T)
    scores_kernel<<<dim3((N + 63) / 64, B / 64), 256, 0, stream>>>(hrbuf, e0, scores, N);
}

// Round 2
// 1902.329 us; speedup vs baseline: 2.1410x; 2.1410x over previous
//
#include <hip/hip_runtime.h>
#include <math.h>

#define DIMV 200
typedef unsigned short ushort;
typedef __attribute__((ext_vector_type(8))) __bf16  bf16x8;
typedef __attribute__((ext_vector_type(4))) float   f32x4;

static __device__ __forceinline__ int lower_bound(const int* __restrict__ a, int n, int key) {
    int lo = 0, hi = n;
    while (lo < hi) {
        int mid = (lo + hi) >> 1;
        if (a[mid] < key) lo = mid + 1; else hi = mid;
    }
    return lo;
}

static __device__ __forceinline__ float gate_fn(float u, float logit) {
    // bias = 1e-4: eps = (2b-1)*u + (1-b); sigmoid((log(eps)-log1p(-eps)+logit)/0.5)
    float ee = fmaf(u, -0.9998f, 0.9999f);
    float g  = (logf(ee) - log1pf(-ee) + logit) * 2.0f;
    return 1.0f / (1.0f + expf(-g));
}

static __device__ __forceinline__ ushort f2bf(float f) {
    unsigned int u = __float_as_uint(f);
    return (ushort)((u + 0x7fffu + ((u >> 16) & 1u)) >> 16);
}

// convert 8 consecutive f32 -> 8 bf16 bit patterns (as ushorts packed in LDS)
static __device__ __forceinline__ void cvt8_store(ushort* dst, const float* src) {
    float4 a = *(const float4*)src;
    float4 b = *(const float4*)(src + 4);
    dst[0] = f2bf(a.x); dst[1] = f2bf(a.y); dst[2] = f2bf(a.z); dst[3] = f2bf(a.w);
    dst[4] = f2bf(b.x); dst[5] = f2bf(b.y); dst[6] = f2bf(b.z); dst[7] = f2bf(b.w);
}
static __device__ __forceinline__ void zero8_store(ushort* dst) {
#pragma unroll
    for (int i = 0; i < 8; i++) dst[i] = 0;
}

// ---------------------------------------------------------------------------
// Prep: W1T[n][k] = bf16(W1[k][n]) zero-padded to [208][KP]
// ---------------------------------------------------------------------------
__global__ __launch_bounds__(256) void transpose_w1_kernel(
    const float* __restrict__ src, ushort* __restrict__ dst, int K, int KP)
{
    int idx = blockIdx.x * 256 + threadIdx.x;
    if (idx >= 208 * KP) return;
    int n = idx / KP, k = idx % KP;
    float v = (n < 200 && k < K) ? src[k * 200 + n] : 0.f;
    dst[idx] = f2bf(v);
}

// ---------------------------------------------------------------------------
// MFMA MLP + concrete gate.  Block tile: 128 rows x 208 hidden, K = KSTEPS*32.
// EDGE: A-row = [e0[erow[e]], e0[ecol[e]]] (K=400 pad 416);
// node: A-row = e0[n] (K=200 pad 224).  Epilogue: relu -> @W2 -> gate.
// 4 waves; wave w owns rows [w*32, w*32+32) (2 M-tiles), all 13 N-tiles.
// ---------------------------------------------------------------------------
template<int KSTEPS, bool EDGE>
__global__ __launch_bounds__(256) void mlp_gate_mfma(
    const float* __restrict__ e0,
    const ushort* __restrict__ W1T,  // [i][208][KSTEPS*32]
    const float* __restrict__ b1,    // [i][200]
    const float* __restrict__ W2,    // [i][200]
    const float* __restrict__ b2,    // [i]
    const float* __restrict__ eps,   // [i][Mtot]
    const int* __restrict__ erow, const int* __restrict__ ecol,
    float* __restrict__ mask_out,    // [i][Mtot]
    int Mtot, int Nnodes)
{
    const int KPW = KSTEPS * 32;
    __shared__ __align__(16) ushort As[2][128 * 40];
    __shared__ __align__(16) ushort Bs[2][208 * 40];
    __shared__ float bsh[208], wsh[208];
    __shared__ int rowv[128], colv[128];

    const int t    = threadIdx.x;
    const int lane = t & 63;
    const int w    = t >> 6;
    const int q    = lane >> 4;
    const int ln   = lane & 15;
    const int i    = EDGE ? 0 : blockIdx.y;
    const int r0   = blockIdx.x * 128;

    const ushort* W1Ti = W1T + (size_t)i * 208 * KPW;
    const float*  b1i  = b1 + i * 200;
    const float*  W2i  = W2 + i * 200;

    if (t < 128) {
        int g = r0 + t;
        if (EDGE) {
            rowv[t] = (g < Mtot) ? erow[g] : -1;
            colv[t] = (g < Mtot) ? ecol[g] : -1;
        } else {
            rowv[t] = (g < Nnodes) ? g : -1;
        }
    }
    if (t < 208) {
        bsh[t] = (t < 200) ? b1i[t] : 0.f;
        wsh[t] = (t < 200) ? W2i[t] : 0.f;
    }
    __syncthreads();

    f32x4 acc[2][13];
#pragma unroll
    for (int mt = 0; mt < 2; mt++)
#pragma unroll
        for (int nt = 0; nt < 13; nt++) {
            acc[mt][nt][0] = 0.f; acc[mt][nt][1] = 0.f;
            acc[mt][nt][2] = 0.f; acc[mt][nt][3] = 0.f;
        }

    // staging lambdas (as macros via helper funcs)
    auto stageA = [&](int ks, int buf) {
#pragma unroll
        for (int it = 0; it < 2; it++) {
            int f = t + it * 256;            // 512 chunks: 128 rows x 4
            int m = f >> 2, c4 = f & 3;
            int C = ks * 4 + c4;             // global 8-chunk index in K
            int node;
            if (EDGE) node = (C < 25) ? rowv[m] : (C < 50 ? colv[m] : -1);
            else      node = (C < 25) ? rowv[m] : -1;
            ushort* dst = &As[buf][m * 40 + c4 * 8];
            if (node >= 0) {
                int koff = (C < 25 ? C : C - 25) << 3;
                cvt8_store(dst, e0 + (size_t)node * 200 + koff);
            } else {
                zero8_store(dst);
            }
        }
    };
    auto stageB = [&](int ks, int buf) {
        for (int f = t; f < 832; f += 256) { // 208 rows x 4
            int n = f >> 2, c4 = f & 3;
            *(bf16x8*)&Bs[buf][n * 40 + c4 * 8] =
                *(const bf16x8*)&W1Ti[n * KPW + ks * 32 + c4 * 8];
        }
    };

    stageA(0, 0);
    stageB(0, 0);
    __syncthreads();

    for (int ks = 0; ks < KSTEPS; ks++) {
        int cur = ks & 1;
        if (ks + 1 < KSTEPS) { stageA(ks + 1, cur ^ 1); stageB(ks + 1, cur ^ 1); }
        bf16x8 af0 = *(const bf16x8*)&As[cur][(w * 32 + ln) * 40 + q * 8];
        bf16x8 af1 = *(const bf16x8*)&As[cur][(w * 32 + 16 + ln) * 40 + q * 8];
#pragma unroll
        for (int nt = 0; nt < 13; nt++) {
            bf16x8 bf = *(const bf16x8*)&Bs[cur][(nt * 16 + ln) * 40 + q * 8];
            acc[0][nt] = __builtin_amdgcn_mfma_f32_16x16x32_bf16(af0, bf, acc[0][nt], 0, 0, 0);
            acc[1][nt] = __builtin_amdgcn_mfma_f32_16x16x32_bf16(af1, bf, acc[1][nt], 0, 0, 0);
        }
        __syncthreads();
    }

    // epilogue: relu(acc + b1) @ W2, reduce over the 16 lanes of each row
    float p[2][4];
#pragma unroll
    for (int mt = 0; mt < 2; mt++)
#pragma unroll
        for (int r = 0; r < 4; r++) {
            float s = 0.f;
#pragma unroll
            for (int nt = 0; nt < 13; nt++) {
                int n = nt * 16 + ln;
                float h = fmaxf(acc[mt][nt][r] + bsh[n], 0.f);
                s = fmaf(h, wsh[n], s);
            }
            p[mt][r] = s;
        }
#pragma unroll
    for (int off = 1; off < 16; off <<= 1)
#pragma unroll
        for (int mt = 0; mt < 2; mt++)
#pragma unroll
            for (int r = 0; r < 4; r++)
                p[mt][r] += __shfl_xor(p[mt][r], off);

    if (ln == 0) {
        float b2v = b2[i];
        const float* epsi = eps + (size_t)i * Mtot;
        float* outi = mask_out + (size_t)i * Mtot;
#pragma unroll
        for (int mt = 0; mt < 2; mt++)
#pragma unroll
            for (int r = 0; r < 4; r++) {
                int row = w * 32 + mt * 16 + q * 4 + r;
                int g = r0 + row;
                if (g < Mtot)
                    outi[g] = gate_fn(epsi[g], p[mt][r] + b2v);
            }
    }
}

// ---------------------------------------------------------------------------
// scores = sigmoid(hr @ e0^T) via MFMA.  Block: 64 b x 192 n, K=200 (7 steps).
// A (hr) fully staged; B = e0 rows (natural layout, inline f32->bf16).
// Waves 2x2: wave (wm,wn) owns rows wm*32..+32, cols wn*96..+96.
// ---------------------------------------------------------------------------
__global__ __launch_bounds__(256) void scores_mfma(
    const float* __restrict__ hr, const float* __restrict__ e0,
    float* __restrict__ scores, int Nent)
{
    __shared__ __align__(16) ushort As[64 * 232];
    __shared__ __align__(16) ushort Bs[2][192 * 40];

    const int t    = threadIdx.x;
    const int lane = t & 63;
    const int w    = t >> 6;
    const int wm   = w >> 1, wn = w & 1;
    const int q    = lane >> 4;
    const int ln   = lane & 15;
    const int n0   = blockIdx.x * 192;
    const int b0   = blockIdx.y * 64;

    // stage A fully: 64 rows x 28 chunks = 1792
    for (int f = t; f < 1792; f += 256) {
        int m = f / 28, c = f % 28;
        ushort* dst = &As[m * 232 + c * 8];
        if (c < 25) cvt8_store(dst, hr + (size_t)(b0 + m) * 200 + c * 8);
        else        zero8_store(dst);
    }

    auto stageB = [&](int ks, int buf) {
        for (int f = t; f < 768; f += 256) { // 192 rows x 4
            int n = f >> 2, c4 = f & 3;
            int k = ks * 32 + c4 * 8;
            int gn = n0 + n;
            ushort* dst = &Bs[buf][n * 40 + c4 * 8];
            if (gn < Nent && k < 200) cvt8_store(dst, e0 + (size_t)gn * 200 + k);
            else                      zero8_store(dst);
        }
    };
    stageB(0, 0);
    __syncthreads();

    f32x4 acc[2][6];
#pragma unroll
    for (int mt = 0; mt < 2; mt++)
#pragma unroll
        for (int nt = 0; nt < 6; nt++) {
            acc[mt][nt][0] = 0.f; acc[mt][nt][1] = 0.f;
            acc[mt][nt][2] = 0.f; acc[mt][nt][3] = 0.f;
        }

    for (int ks = 0; ks < 7; ks++) {
        int cur = ks & 1;
        if (ks + 1 < 7) stageB(ks + 1, cur ^ 1);
        bf16x8 af0 = *(const bf16x8*)&As[(wm * 32 + ln) * 232 + ks * 32 + q * 8];
        bf16x8 af1 = *(const bf16x8*)&As[(wm * 32 + 16 + ln) * 232 + ks * 32 + q * 8];
#pragma unroll
        for (int nt = 0; nt < 6; nt++) {
            bf16x8 bf = *(const bf16x8*)&Bs[cur][(wn * 96 + nt * 16 + ln) * 40 + q * 8];
            acc[0][nt] = __builtin_amdgcn_mfma_f32_16x16x32_bf16(af0, bf, acc[0][nt], 0, 0, 0);
            acc[1][nt] = __builtin_amdgcn_mfma_f32_16x16x32_bf16(af1, bf, acc[1][nt], 0, 0, 0);
        }
        __syncthreads();
    }

#pragma unroll
    for (int mt = 0; mt < 2; mt++) {
        int b = b0 + wm * 32 + mt * 16 + q * 4;
#pragma unroll
        for (int nt = 0; nt < 6; nt++) {
            int n = n0 + wn * 96 + nt * 16 + ln;
            if (n < Nent) {
#pragma unroll
                for (int r = 0; r < 4; r++)
                    scores[(size_t)(b + r) * Nent + n] = 1.f / (1.f + __expf(-acc[mt][nt][r]));
            }
        }
    }
}

// ---------------------------------------------------------------------------
// SpMM over sorted COO: out[r,:] = sum_e val[e]*(emask?emask[e]:1)*x[col[e],:]
// ---------------------------------------------------------------------------
__global__ __launch_bounds__(256) void spmm_kernel(
    const float* __restrict__ x, const int* __restrict__ row,
    const int* __restrict__ col, const float* __restrict__ val,
    const float* __restrict__ emask, int E, float* __restrict__ out)
{
    __shared__ int bnds[2];
    const int r = blockIdx.x;
    if (threadIdx.x == 0) {
        bnds[0] = lower_bound(row, E, r);
        bnds[1] = lower_bound(row, E, r + 1);
    }
    __syncthreads();
    const int d = threadIdx.x;
    if (d >= DIMV) return;
    const int lo = bnds[0], hi = bnds[1];
    float acc = 0.f;
    if (emask) {
        for (int e = lo; e < hi; e++)
            acc = fmaf(val[e] * emask[e], x[col[e] * DIMV + d], acc);
    } else {
        for (int e = lo; e < hi; e++)
            acc = fmaf(val[e], x[col[e] * DIMV + d], acc);
    }
    out[r * DIMV + d] = acc;
}

__global__ __launch_bounds__(256) void rw_combine_kernel(
    const float* __restrict__ x, const int* __restrict__ row,
    const int* __restrict__ col, const float* __restrict__ val,
    int E, const float* __restrict__ mask, float* __restrict__ out)
{
    __shared__ int bnds[2];
    const int r = blockIdx.x;
    if (threadIdx.x == 0) {
        bnds[0] = lower_bound(row, E, r);
        bnds[1] = lower_bound(row, E, r + 1);
    }
    __syncthreads();
    const int d = threadIdx.x;
    if (d >= DIMV) return;
    const int lo = bnds[0], hi = bnds[1];
    float acc = 0.f;
    for (int e = lo; e < hi; e++)
        acc = fmaf(val[e], x[col[e] * DIMV + d], acc);
    const float m = mask[r];
    out[r * DIMV + d] = m * x[r * DIMV + d] + (1.f - m) * acc;
}

__global__ __launch_bounds__(256) void selfhr_kernel(
    const float* __restrict__ e0, const float* __restrict__ rel_emb,
    const int* __restrict__ sub, const int* __restrict__ rel,
    float* __restrict__ out)
{
    const int b = blockIdx.x;
    __shared__ float lhs[DIMV];
    const int t = threadIdx.x;
    if (t < DIMV) lhs[t] = e0[sub[b] * DIMV + t];
    __syncthreads();
    if (t >= DIMV) return;
    const float* R = rel_emb + (size_t)rel[b] * (DIMV * DIMV);
    float acc = 0.f;
    for (int dd = 0; dd < DIMV; dd++)
        acc = fmaf(lhs[dd], R[dd * DIMV + t], acc);
    out[b * DIMV + t] = acc;
}

extern "C" void kernel_launch(void* const* d_in, const int* in_sizes, int n_in,
                              void* d_out, int out_size, void* d_ws, size_t ws_size,
                              hipStream_t stream)
{
    const float* e0       = (const float*)d_in[0];
    const float* rel_emb  = (const float*)d_in[1];
    const float* node_W1  = (const float*)d_in[2];
    const float* node_b1  = (const float*)d_in[3];
    const float* node_W2  = (const float*)d_in[4];
    const float* node_b2  = (const float*)d_in[5];
    const float* edge_W1  = (const float*)d_in[6];
    const float* edge_b1  = (const float*)d_in[7];
    const float* edge_W2  = (const float*)d_in[8];
    const float* edge_b2  = (const float*)d_in[9];
    const int*   adj_row  = (const int*)d_in[10];
    const int*   adj_col  = (const int*)d_in[11];
    const float* adj_val  = (const float*)d_in[12];
    const int*   rw_row   = (const int*)d_in[13];
    const int*   rw_col   = (const int*)d_in[14];
    const float* rw_val   = (const float*)d_in[15];
    const float* node_eps = (const float*)d_in[16];
    const float* edge_eps = (const float*)d_in[17];
    const int*   sub      = (const int*)d_in[18];
    const int*   rel      = (const int*)d_in[19];

    const int E   = in_sizes[10];
    const int Erw = in_sizes[13];
    const int N   = in_sizes[0] / DIMV;   // 50000
    const int B   = in_sizes[18];         // 1024

    // workspace layout (floats): W1eT | W1nT | hr | node_mask | edge_mask
    float*  ws        = (float*)d_ws;
    ushort* W1eT      = (ushort*)ws;                       // 208*416 ush = 43264 f
    ushort* W1nT      = (ushort*)(ws + 43264);             // 2*208*224 ush = 46592 f
    float*  hrbuf     = ws + 43264 + 46592;                // B*200
    float*  node_mask = hrbuf + (size_t)B * DIMV;          // 2*N
    float*  edge_mask = node_mask + 2 * (size_t)N;         // E

    // output layout: scores (B*N), x_nd (N*200), x_ed (N*200)
    float* out    = (float*)d_out;
    float* scores = out;
    float* x_nd   = out + (size_t)B * N;
    float* x_ed   = x_nd + (size_t)N * DIMV;
    // scores region doubles as two N*200 temporaries until the GEMM (last) runs
    float* T  = scores;
    float* T2 = scores + (size_t)N * DIMV;

    // 0. weight transposes (bf16, padded)
    transpose_w1_kernel<<<(208 * 416 + 255) / 256, 256, 0, stream>>>(
        edge_W1 + 400 * 200, W1eT, 400, 416);
    transpose_w1_kernel<<<(208 * 224 + 255) / 256, 256, 0, stream>>>(
        node_W1, W1nT, 200, 224);
    transpose_w1_kernel<<<(208 * 224 + 255) / 256, 256, 0, stream>>>(
        node_W1 + 200 * 200, W1nT + 208 * 224, 200, 224);

    // 1. edge mask (i=1 slice only; i=0 edge mask is dead in the reference)
    mlp_gate_mfma<13, true><<<dim3((E + 127) / 128), 256, 0, stream>>>(
        e0, W1eT, edge_b1 + 200, edge_W2 + 200, edge_b2 + 1,
        edge_eps + (size_t)E, adj_row, adj_col, edge_mask, E, N);

    // 2. node masks (both i)
    mlp_gate_mfma<7, false><<<dim3((N + 127) / 128, 2), 256, 0, stream>>>(
        e0, W1nT, node_b1, node_W2, node_b2,
        node_eps, nullptr, nullptr, node_mask, N, N);

    // 3-5. edge-drop branch: x_ed = adj_spmm(masked, rw_spmm(rw_spmm(e0)))
    spmm_kernel<<<N, 256, 0, stream>>>(e0,   rw_row, rw_col, rw_val, nullptr, Erw, x_nd);
    spmm_kernel<<<N, 256, 0, stream>>>(x_nd, rw_row, rw_col, rw_val, nullptr, Erw, T);
    spmm_kernel<<<N, 256, 0, stream>>>(T, adj_row, adj_col, adj_val, edge_mask, E, x_ed);

    // 6-9. node-drop branch
    rw_combine_kernel<<<N, 256, 0, stream>>>(e0, rw_row, rw_col, rw_val, Erw, node_mask,     x_nd);
    spmm_kernel      <<<N, 256, 0, stream>>>(x_nd, adj_row, adj_col, adj_val, nullptr, E,    T);
    rw_combine_kernel<<<N, 256, 0, stream>>>(T,  rw_row, rw_col, rw_val, Erw, node_mask + N, T2);
    spmm_kernel      <<<N, 256, 0, stream>>>(T2, adj_row, adj_col, adj_val, nullptr, E,      x_nd);

    // 10. self_hr (f32)
    selfhr_kernel<<<B, 256, 0, stream>>>(e0, rel_emb, sub, rel, hrbuf);

    // 11. scores = sigmoid(self_hr @ e0^T) via MFMA
    scores_mfma<<<dim3((N + 191) / 192, B / 64), 256, 0, stream>>>(hrbuf, e0, scores, N);
}

// Round 3
// 1165.213 us; speedup vs baseline: 3.4955x; 1.6326x over previous
//
#include <hip/hip_runtime.h>
#include <math.h>

#define DIMV 200
typedef unsigned short ushort;
typedef __attribute__((ext_vector_type(8))) __bf16  bf16x8;
typedef __attribute__((ext_vector_type(4))) float   f32x4;

static __device__ __forceinline__ int lower_bound(const int* __restrict__ a, int n, int key) {
    int lo = 0, hi = n;
    while (lo < hi) {
        int mid = (lo + hi) >> 1;
        if (a[mid] < key) lo = mid + 1; else hi = mid;
    }
    return lo;
}

static __device__ __forceinline__ float gate_fn(float u, float logit) {
    // bias = 1e-4: eps = (2b-1)*u + (1-b); sigmoid((log(eps)-log1p(-eps)+logit)/0.5)
    float ee = fmaf(u, -0.9998f, 0.9999f);
    float g  = (logf(ee) - log1pf(-ee) + logit) * 2.0f;
    return 1.0f / (1.0f + expf(-g));
}

static __device__ __forceinline__ ushort f2bf(float f) {
    unsigned int u = __float_as_uint(f);
    return (ushort)((u + 0x7fffu + ((u >> 16) & 1u)) >> 16);
}

static __device__ __forceinline__ void cvt8_store(ushort* dst, const float* src) {
    float4 a = *(const float4*)src;
    float4 b = *(const float4*)(src + 4);
    dst[0] = f2bf(a.x); dst[1] = f2bf(a.y); dst[2] = f2bf(a.z); dst[3] = f2bf(a.w);
    dst[4] = f2bf(b.x); dst[5] = f2bf(b.y); dst[6] = f2bf(b.z); dst[7] = f2bf(b.w);
}
static __device__ __forceinline__ void zero8_store(ushort* dst) {
#pragma unroll
    for (int i = 0; i < 8; i++) dst[i] = 0;
}

// ---------------------------------------------------------------------------
// e0bf[n][0..223] = bf16(e0[n][k]) (zero-pad k>=200).  One 8-chunk per thread.
// ---------------------------------------------------------------------------
__global__ __launch_bounds__(256) void e0bf_kernel(
    const float* __restrict__ e0, ushort* __restrict__ e0bf, int N)
{
    int idx = blockIdx.x * 256 + threadIdx.x;   // chunk index: N*28
    if (idx >= N * 28) return;
    int n = idx / 28, c = idx % 28;
    ushort* dst = e0bf + (size_t)n * 224 + c * 8;
    if (c < 25) cvt8_store(dst, e0 + (size_t)n * 200 + c * 8);
    else        zero8_store(dst);
}

// ---------------------------------------------------------------------------
// Edge W1 combined transpose: B[k][n] = n<200 ? W1e[k][n] : W1e[k+200][n-200]
// dst[n][k] bf16, n<416, k<224 (zero pad)
// ---------------------------------------------------------------------------
__global__ __launch_bounds__(256) void transpose_w1e_kernel(
    const float* __restrict__ src, ushort* __restrict__ dst)
{
    int idx = blockIdx.x * 256 + threadIdx.x;
    if (idx >= 416 * 224) return;
    int n = idx / 224, k = idx % 224;
    float v = 0.f;
    if (k < 200) {
        if (n < 200)      v = src[k * 200 + n];
        else if (n < 400) v = src[(k + 200) * 200 + (n - 200)];
    }
    dst[idx] = f2bf(v);
}

// Node W1 transpose: dst[i][n][k] (208 x 224, zero-pad), src (i,200,200) k-major
__global__ __launch_bounds__(256) void transpose_w1n_kernel(
    const float* __restrict__ src, ushort* __restrict__ dst)
{
    int idx = blockIdx.x * 256 + threadIdx.x;
    int i = blockIdx.y;
    if (idx >= 208 * 224) return;
    int n = idx / 224, k = idx % 224;
    float v = (n < 200 && k < 200) ? src[i * 40000 + k * 200 + n] : 0.f;
    dst[(size_t)i * 208 * 224 + idx] = f2bf(v);
}

// rowptr[r] = lower_bound(row, E, r), r in [0, N]
__global__ __launch_bounds__(256) void rowptr_kernel(
    const int* __restrict__ row, int E, int N, int* __restrict__ rowptr)
{
    int r = blockIdx.x * 256 + threadIdx.x;
    if (r <= N) rowptr[r] = lower_bound(row, E, r);
}

// ---------------------------------------------------------------------------
// Plain GEMM: C[m][n] = sum_k A[m][k]*B[k][n], A = e0bf (M x 224 bf16),
// B^T = W1T (NTILES*208 x 224 bf16).  Block: 128m x 208n, grid (M/128, NTILES).
// C written f32 with row stride Cld, cols clipped to Nvalid.
// ---------------------------------------------------------------------------
__global__ __launch_bounds__(256) void gemm_e0_kernel(
    const ushort* __restrict__ e0bf, const ushort* __restrict__ W1T,
    float* __restrict__ C, int M, int Cld, int Nvalid)
{
    __shared__ __align__(16) ushort As[2][128 * 40];
    __shared__ __align__(16) ushort Bs[2][208 * 40];

    const int t    = threadIdx.x;
    const int lane = t & 63;
    const int w    = t >> 6;
    const int q    = lane >> 4;
    const int ln   = lane & 15;
    const int r0   = blockIdx.x * 128;
    const int nb   = blockIdx.y;               // 208-col tile
    const ushort* Wt = W1T + (size_t)nb * 208 * 224;

    f32x4 acc[2][13];
#pragma unroll
    for (int mt = 0; mt < 2; mt++)
#pragma unroll
        for (int nt = 0; nt < 13; nt++) {
            acc[mt][nt][0] = 0.f; acc[mt][nt][1] = 0.f;
            acc[mt][nt][2] = 0.f; acc[mt][nt][3] = 0.f;
        }

    auto stageA = [&](int ks, int buf) {
#pragma unroll
        for (int it = 0; it < 2; it++) {
            int f = t + it * 256;
            int m = f >> 2, c4 = f & 3;
            int g = r0 + m;
            ushort* dst = &As[buf][m * 40 + c4 * 8];
            if (g < M) *(bf16x8*)dst = *(const bf16x8*)&e0bf[(size_t)g * 224 + ks * 32 + c4 * 8];
            else       zero8_store(dst);
        }
    };
    auto stageB = [&](int ks, int buf) {
        for (int f = t; f < 832; f += 256) {
            int n = f >> 2, c4 = f & 3;
            *(bf16x8*)&Bs[buf][n * 40 + c4 * 8] =
                *(const bf16x8*)&Wt[(size_t)n * 224 + ks * 32 + c4 * 8];
        }
    };

    stageA(0, 0); stageB(0, 0);
    __syncthreads();

    for (int ks = 0; ks < 7; ks++) {
        int cur = ks & 1;
        if (ks + 1 < 7) { stageA(ks + 1, cur ^ 1); stageB(ks + 1, cur ^ 1); }
        bf16x8 af0 = *(const bf16x8*)&As[cur][(w * 32 + ln) * 40 + q * 8];
        bf16x8 af1 = *(const bf16x8*)&As[cur][(w * 32 + 16 + ln) * 40 + q * 8];
#pragma unroll
        for (int nt = 0; nt < 13; nt++) {
            bf16x8 bf = *(const bf16x8*)&Bs[cur][(nt * 16 + ln) * 40 + q * 8];
            acc[0][nt] = __builtin_amdgcn_mfma_f32_16x16x32_bf16(af0, bf, acc[0][nt], 0, 0, 0);
            acc[1][nt] = __builtin_amdgcn_mfma_f32_16x16x32_bf16(af1, bf, acc[1][nt], 0, 0, 0);
        }
        __syncthreads();
    }

#pragma unroll
    for (int mt = 0; mt < 2; mt++) {
        int gm = r0 + w * 32 + mt * 16 + q * 4;
#pragma unroll
        for (int nt = 0; nt < 13; nt++) {
            int gn = nb * 208 + nt * 16 + ln;
            if (gn < Nvalid) {
#pragma unroll
                for (int r = 0; r < 4; r++)
                    if (gm + r < M) C[(size_t)(gm + r) * Cld + gn] = acc[mt][nt][r];
            }
        }
    }
}

// ---------------------------------------------------------------------------
// Edge gate epilogue: logit_e = relu(P[row][d] + P[col][200+d] + b1[d]) . W2 + b2
// One wave per contiguous edge chunk (row-locality: edges sorted by row).
// ---------------------------------------------------------------------------
__global__ __launch_bounds__(256) void edge_gate_kernel(
    const float* __restrict__ P, const float* __restrict__ b1,
    const float* __restrict__ W2, const float* __restrict__ b2,
    const float* __restrict__ eps, const int* __restrict__ erow,
    const int* __restrict__ ecol, float* __restrict__ mask_out, int E)
{
    const int lane = threadIdx.x & 63;
    const int wave = (blockIdx.x * 256 + threadIdx.x) >> 6;
    const int nw   = gridDim.x * 4;
    const int chunk = (E + nw - 1) / nw;
    const int e_lo = wave * chunk;
    const int e_hi = min(e_lo + chunk, E);

    float bb[4], ww[4];
#pragma unroll
    for (int j = 0; j < 4; j++) {
        int d = lane + j * 64;
        bool v = d < 200;
        bb[j] = v ? b1[d] : 0.f;
        ww[j] = v ? W2[d] : 0.f;
    }
    const float b2v = b2[0];

    for (int e = e_lo; e < e_hi; e++) {
        const float* pr = P + (size_t)erow[e] * 400;
        const float* pc = P + (size_t)ecol[e] * 400 + 200;
        float s = 0.f;
#pragma unroll
        for (int j = 0; j < 4; j++) {
            int d = lane + j * 64;
            if (d < 200)
                s = fmaf(fmaxf(pr[d] + pc[d] + bb[j], 0.f), ww[j], s);
        }
#pragma unroll
        for (int off = 32; off; off >>= 1) s += __shfl_xor(s, off);
        if (lane == 0) mask_out[e] = gate_fn(eps[e], s + b2v);
    }
}

// ---------------------------------------------------------------------------
// Node MLP + gate via MFMA.  Block 128 rows x 208 hidden, K=224 (7 steps).
// A from e0bf (contiguous rows).  grid = (ceil(N/128), 2).
// ---------------------------------------------------------------------------
__global__ __launch_bounds__(256) void node_mlp_mfma(
    const ushort* __restrict__ e0bf,
    const ushort* __restrict__ W1T,  // [i][208][224]
    const float* __restrict__ b1, const float* __restrict__ W2,
    const float* __restrict__ b2, const float* __restrict__ eps,
    float* __restrict__ mask_out, int N)
{
    __shared__ __align__(16) ushort As[2][128 * 40];
    __shared__ __align__(16) ushort Bs[2][208 * 40];
    __shared__ float bsh[208], wsh[208];

    const int t    = threadIdx.x;
    const int lane = t & 63;
    const int w    = t >> 6;
    const int q    = lane >> 4;
    const int ln   = lane & 15;
    const int i    = blockIdx.y;
    const int r0   = blockIdx.x * 128;
    const ushort* Wt = W1T + (size_t)i * 208 * 224;

    if (t < 208) {
        bsh[t] = (t < 200) ? b1[i * 200 + t] : 0.f;
        wsh[t] = (t < 200) ? W2[i * 200 + t] : 0.f;
    }

    f32x4 acc[2][13];
#pragma unroll
    for (int mt = 0; mt < 2; mt++)
#pragma unroll
        for (int nt = 0; nt < 13; nt++) {
            acc[mt][nt][0] = 0.f; acc[mt][nt][1] = 0.f;
            acc[mt][nt][2] = 0.f; acc[mt][nt][3] = 0.f;
        }

    auto stageA = [&](int ks, int buf) {
#pragma unroll
        for (int it = 0; it < 2; it++) {
            int f = t + it * 256;
            int m = f >> 2, c4 = f & 3;
            int g = r0 + m;
            ushort* dst = &As[buf][m * 40 + c4 * 8];
            if (g < N) *(bf16x8*)dst = *(const bf16x8*)&e0bf[(size_t)g * 224 + ks * 32 + c4 * 8];
            else       zero8_store(dst);
        }
    };
    auto stageB = [&](int ks, int buf) {
        for (int f = t; f < 832; f += 256) {
            int n = f >> 2, c4 = f & 3;
            *(bf16x8*)&Bs[buf][n * 40 + c4 * 8] =
                *(const bf16x8*)&Wt[(size_t)n * 224 + ks * 32 + c4 * 8];
        }
    };

    stageA(0, 0); stageB(0, 0);
    __syncthreads();

    for (int ks = 0; ks < 7; ks++) {
        int cur = ks & 1;
        if (ks + 1 < 7) { stageA(ks + 1, cur ^ 1); stageB(ks + 1, cur ^ 1); }
        bf16x8 af0 = *(const bf16x8*)&As[cur][(w * 32 + ln) * 40 + q * 8];
        bf16x8 af1 = *(const bf16x8*)&As[cur][(w * 32 + 16 + ln) * 40 + q * 8];
#pragma unroll
        for (int nt = 0; nt < 13; nt++) {
            bf16x8 bf = *(const bf16x8*)&Bs[cur][(nt * 16 + ln) * 40 + q * 8];
            acc[0][nt] = __builtin_amdgcn_mfma_f32_16x16x32_bf16(af0, bf, acc[0][nt], 0, 0, 0);
            acc[1][nt] = __builtin_amdgcn_mfma_f32_16x16x32_bf16(af1, bf, acc[1][nt], 0, 0, 0);
        }
        __syncthreads();
    }

    float p[2][4];
#pragma unroll
    for (int mt = 0; mt < 2; mt++)
#pragma unroll
        for (int r = 0; r < 4; r++) {
            float s = 0.f;
#pragma unroll
            for (int nt = 0; nt < 13; nt++) {
                int n = nt * 16 + ln;
                float h = fmaxf(acc[mt][nt][r] + bsh[n], 0.f);
                s = fmaf(h, wsh[n], s);
            }
            p[mt][r] = s;
        }
#pragma unroll
    for (int off = 1; off < 16; off <<= 1)
#pragma unroll
        for (int mt = 0; mt < 2; mt++)
#pragma unroll
            for (int r = 0; r < 4; r++)
                p[mt][r] += __shfl_xor(p[mt][r], off);

    if (ln == 0) {
        float b2v = b2[i];
        const float* epsi = eps + (size_t)i * N;
        float* outi = mask_out + (size_t)i * N;
#pragma unroll
        for (int mt = 0; mt < 2; mt++)
#pragma unroll
            for (int r = 0; r < 4; r++) {
                int g = r0 + w * 32 + mt * 16 + q * 4 + r;
                if (g < N) outi[g] = gate_fn(epsi[g], p[mt][r] + b2v);
            }
    }
}

// ---------------------------------------------------------------------------
// scores = sigmoid(hr @ e0^T) via MFMA, A = hrbf, B = e0bf (pure copies).
// Block 64b x 192n, K=224 (7 steps), grid (ceil(N/192), 16).
// ---------------------------------------------------------------------------
__global__ __launch_bounds__(256) void scores_mfma(
    const ushort* __restrict__ hrbf, const ushort* __restrict__ e0bf,
    float* __restrict__ scores, int Nent)
{
    __shared__ __align__(16) ushort As[64 * 232];
    __shared__ __align__(16) ushort Bs[2][192 * 40];

    const int t    = threadIdx.x;
    const int lane = t & 63;
    const int w    = t >> 6;
    const int wm   = w >> 1, wn = w & 1;
    const int q    = lane >> 4;
    const int ln   = lane & 15;
    const int n0   = blockIdx.x * 192;
    const int b0   = blockIdx.y * 64;

    for (int f = t; f < 1792; f += 256) {
        int m = f / 28, c = f % 28;
        *(bf16x8*)&As[m * 232 + c * 8] = *(const bf16x8*)&hrbf[(size_t)(b0 + m) * 224 + c * 8];
    }

    auto stageB = [&](int ks, int buf) {
        for (int f = t; f < 768; f += 256) {
            int n = f >> 2, c4 = f & 3;
            int gn = n0 + n;
            ushort* dst = &Bs[buf][n * 40 + c4 * 8];
            if (gn < Nent) *(bf16x8*)dst = *(const bf16x8*)&e0bf[(size_t)gn * 224 + ks * 32 + c4 * 8];
            else           zero8_store(dst);
        }
    };
    stageB(0, 0);
    __syncthreads();

    f32x4 acc[2][6];
#pragma unroll
    for (int mt = 0; mt < 2; mt++)
#pragma unroll
        for (int nt = 0; nt < 6; nt++) {
            acc[mt][nt][0] = 0.f; acc[mt][nt][1] = 0.f;
            acc[mt][nt][2] = 0.f; acc[mt][nt][3] = 0.f;
        }

    for (int ks = 0; ks < 7; ks++) {
        int cur = ks & 1;
        if (ks + 1 < 7) stageB(ks + 1, cur ^ 1);
        bf16x8 af0 = *(const bf16x8*)&As[(wm * 32 + ln) * 232 + ks * 32 + q * 8];
        bf16x8 af1 = *(const bf16x8*)&As[(wm * 32 + 16 + ln) * 232 + ks * 32 + q * 8];
#pragma unroll
        for (int nt = 0; nt < 6; nt++) {
            bf16x8 bf = *(const bf16x8*)&Bs[cur][(wn * 96 + nt * 16 + ln) * 40 + q * 8];
            acc[0][nt] = __builtin_amdgcn_mfma_f32_16x16x32_bf16(af0, bf, acc[0][nt], 0, 0, 0);
            acc[1][nt] = __builtin_amdgcn_mfma_f32_16x16x32_bf16(af1, bf, acc[1][nt], 0, 0, 0);
        }
        __syncthreads();
    }

#pragma unroll
    for (int mt = 0; mt < 2; mt++) {
        int b = b0 + wm * 32 + mt * 16 + q * 4;
#pragma unroll
        for (int nt = 0; nt < 6; nt++) {
            int n = n0 + wn * 96 + nt * 16 + ln;
            if (n < Nent) {
#pragma unroll
                for (int r = 0; r < 4; r++)
                    scores[(size_t)(b + r) * Nent + n] = 1.f / (1.f + __expf(-acc[mt][nt][r]));
            }
        }
    }
}

// ---------------------------------------------------------------------------
// SpMM (CSR ranges via rowptr): out[r,:] = sum val*(emask?)*x[col[e],:]
// ---------------------------------------------------------------------------
__global__ __launch_bounds__(256) void spmm_kernel(
    const float* __restrict__ x, const int* __restrict__ rowptr,
    const int* __restrict__ col, const float* __restrict__ val,
    const float* __restrict__ emask, float* __restrict__ out)
{
    const int r = blockIdx.x;
    const int d = threadIdx.x;
    if (d >= DIMV) return;
    const int lo = rowptr[r], hi = rowptr[r + 1];
    float a0 = 0.f, a1 = 0.f;
    int e = lo;
    if (emask) {
        for (; e + 1 < hi; e += 2) {
            a0 = fmaf(val[e] * emask[e],         x[(size_t)col[e] * DIMV + d],     a0);
            a1 = fmaf(val[e + 1] * emask[e + 1], x[(size_t)col[e + 1] * DIMV + d], a1);
        }
        if (e < hi) a0 = fmaf(val[e] * emask[e], x[(size_t)col[e] * DIMV + d], a0);
    } else {
        for (; e + 1 < hi; e += 2) {
            a0 = fmaf(val[e],     x[(size_t)col[e] * DIMV + d],     a0);
            a1 = fmaf(val[e + 1], x[(size_t)col[e + 1] * DIMV + d], a1);
        }
        if (e < hi) a0 = fmaf(val[e], x[(size_t)col[e] * DIMV + d], a0);
    }
    out[(size_t)r * DIMV + d] = a0 + a1;
}

__global__ __launch_bounds__(256) void rw_combine_kernel(
    const float* __restrict__ x, const int* __restrict__ rowptr,
    const int* __restrict__ col, const float* __restrict__ val,
    const float* __restrict__ mask, float* __restrict__ out)
{
    const int r = blockIdx.x;
    const int d = threadIdx.x;
    if (d >= DIMV) return;
    const int lo = rowptr[r], hi = rowptr[r + 1];
    float a0 = 0.f, a1 = 0.f;
    int e = lo;
    for (; e + 1 < hi; e += 2) {
        a0 = fmaf(val[e],     x[(size_t)col[e] * DIMV + d],     a0);
        a1 = fmaf(val[e + 1], x[(size_t)col[e + 1] * DIMV + d], a1);
    }
    if (e < hi) a0 = fmaf(val[e], x[(size_t)col[e] * DIMV + d], a0);
    const float m = mask[r];
    out[(size_t)r * DIMV + d] = m * x[(size_t)r * DIMV + d] + (1.f - m) * (a0 + a1);
}

// self_hr -> bf16 (stride 224, zero-padded)
__global__ __launch_bounds__(256) void selfhr_kernel(
    const float* __restrict__ e0, const float* __restrict__ rel_emb,
    const int* __restrict__ sub, const int* __restrict__ rel,
    ushort* __restrict__ hrbf)
{
    const int b = blockIdx.x;
    __shared__ float lhs[DIMV];
    const int t = threadIdx.x;
    if (t < DIMV) lhs[t] = e0[(size_t)sub[b] * DIMV + t];
    __syncthreads();
    if (t >= 224) return;
    if (t < DIMV) {
        const float* R = rel_emb + (size_t)rel[b] * (DIMV * DIMV);
        float acc = 0.f;
        for (int dd = 0; dd < DIMV; dd++)
            acc = fmaf(lhs[dd], R[dd * DIMV + t], acc);
        hrbf[(size_t)b * 224 + t] = f2bf(acc);
    } else {
        hrbf[(size_t)b * 224 + t] = 0;
    }
}

extern "C" void kernel_launch(void* const* d_in, const int* in_sizes, int n_in,
                              void* d_out, int out_size, void* d_ws, size_t ws_size,
                              hipStream_t stream)
{
    const float* e0       = (const float*)d_in[0];
    const float* rel_emb  = (const float*)d_in[1];
    const float* node_W1  = (const float*)d_in[2];
    const float* node_b1  = (const float*)d_in[3];
    const float* node_W2  = (const float*)d_in[4];
    const float* node_b2  = (const float*)d_in[5];
    const float* edge_W1  = (const float*)d_in[6];
    const float* edge_b1  = (const float*)d_in[7];
    const float* edge_W2  = (const float*)d_in[8];
    const float* edge_b2  = (const float*)d_in[9];
    const int*   adj_row  = (const int*)d_in[10];
    const int*   adj_col  = (const int*)d_in[11];
    const float* adj_val  = (const float*)d_in[12];
    const int*   rw_row   = (const int*)d_in[13];
    const int*   rw_col   = (const int*)d_in[14];
    const float* rw_val   = (const float*)d_in[15];
    const float* node_eps = (const float*)d_in[16];
    const float* edge_eps = (const float*)d_in[17];
    const int*   sub      = (const int*)d_in[18];
    const int*   rel      = (const int*)d_in[19];

    const int E   = in_sizes[10];
    const int Erw = in_sizes[13];
    const int N   = in_sizes[0] / DIMV;   // 50000
    const int B   = in_sizes[18];         // 1024

    // workspace layout (~25.6 MB)
    ushort* W1eT = (ushort*)d_ws;                      // 416*224
    ushort* W1nT = W1eT + 416 * 224;                   // 2*208*224
    ushort* e0bf = W1nT + 2 * 208 * 224;               // N*224
    ushort* hrbf = e0bf + (size_t)N * 224;             // B*224
    float*  fb   = (float*)(hrbf + (size_t)B * 224);
    float*  node_mask = fb;                            // 2*N
    float*  edge_mask = node_mask + 2 * (size_t)N;     // E
    int*    rp_adj = (int*)(edge_mask + E);            // N+1
    int*    rp_rw  = rp_adj + (N + 1);                 // N+1

    // output layout: scores (B*N), x_nd (N*200), x_ed (N*200)
    float* out    = (float*)d_out;
    float* scores = out;
    float* x_nd   = out + (size_t)B * N;
    float* x_ed   = x_nd + (size_t)N * DIMV;
    // scores region as scratch until the final GEMM:
    float* T  = scores;                                // N*200
    float* T2 = scores + (size_t)N * DIMV;             // N*200
    float* P  = scores + 2 * (size_t)N * DIMV;         // N*400 (edge-MLP hidden pre-acts)

    // 0. preps
    e0bf_kernel<<<(N * 28 + 255) / 256, 256, 0, stream>>>(e0, e0bf, N);
    transpose_w1e_kernel<<<(416 * 224 + 255) / 256, 256, 0, stream>>>(edge_W1 + 400 * 200, W1eT);
    transpose_w1n_kernel<<<dim3((208 * 224 + 255) / 256, 2), 256, 0, stream>>>(node_W1, W1nT);
    rowptr_kernel<<<(N + 256) / 256, 256, 0, stream>>>(adj_row, E,   N, rp_adj);
    rowptr_kernel<<<(N + 256) / 256, 256, 0, stream>>>(rw_row,  Erw, N, rp_rw);

    // 1. edge path: P = e0 @ [W1a|W1b]  (node-level), then per-edge gate
    gemm_e0_kernel<<<dim3((N + 127) / 128, 2), 256, 0, stream>>>(e0bf, W1eT, P, N, 400, 400);
    edge_gate_kernel<<<6144, 256, 0, stream>>>(
        P, edge_b1 + 200, edge_W2 + 200, edge_b2 + 1, edge_eps + (size_t)E,
        adj_row, adj_col, edge_mask, E);

    // 2. node masks (both i)
    node_mlp_mfma<<<dim3((N + 127) / 128, 2), 256, 0, stream>>>(
        e0bf, W1nT, node_b1, node_W2, node_b2, node_eps, node_mask, N);

    // 3-5. edge-drop branch: x_ed = adj_spmm(masked, rw_spmm(rw_spmm(e0)))
    spmm_kernel<<<N, 256, 0, stream>>>(e0,   rp_rw, rw_col, rw_val, nullptr, x_nd);
    spmm_kernel<<<N, 256, 0, stream>>>(x_nd, rp_rw, rw_col, rw_val, nullptr, T);
    spmm_kernel<<<N, 256, 0, stream>>>(T, rp_adj, adj_col, adj_val, edge_mask, x_ed);

    // 6-9. node-drop branch
    rw_combine_kernel<<<N, 256, 0, stream>>>(e0, rp_rw, rw_col, rw_val, node_mask,     x_nd);
    spmm_kernel      <<<N, 256, 0, stream>>>(x_nd, rp_adj, adj_col, adj_val, nullptr,  T);
    rw_combine_kernel<<<N, 256, 0, stream>>>(T,  rp_rw, rw_col, rw_val, node_mask + N, T2);
    spmm_kernel      <<<N, 256, 0, stream>>>(T2, rp_adj, adj_col, adj_val, nullptr,    x_nd);

    // 10. self_hr -> bf16
    selfhr_kernel<<<B, 256, 0, stream>>>(e0, rel_emb, sub, rel, hrbf);

    // 11. scores = sigmoid(self_hr @ e0^T) via MFMA
    scores_mfma<<<dim3((N + 191) / 192, B / 64), 256, 0, stream>>>(hrbf, e0bf, scores, N);
}